// Round 9
// baseline (151.709 us; speedup 1.0000x reference)
//
#include <hip/hip_runtime.h>
#include <hip/hip_bf16.h>

// FeatureAlign deformable 3x3 conv, G=4, PAD=1.
// R9: N=128 per block (2b x 64w), 1024 threads, 256 blocks -> weight L2
// traffic halved (604->302 MB) at constant 16 waves/CU. Full meta doesn't fit
// LDS; since gk/9 == g, meta is phase-buffered per group (18.4 KB) and
// recomputed at gk = 7/16/25 (old phase's last read is at gk-1's issue).
// Pipeline/commit/issue identical to R8 otherwise.

#define Bn   8
#define CIN  256
#define COUT 256
#define Hn   64
#define Wn   64
#define Gn   4
#define Kn   9
#define CPG  64
#define GK   36

typedef __bf16 bf16x8 __attribute__((ext_vector_type(8)));
typedef float  f32x4  __attribute__((ext_vector_type(4)));
typedef _Float16 f16x2 __attribute__((ext_vector_type(2)));

// ---------------------------------------------------------------------------
// Fused prep (unchanged).
//  blocks [0, 4096):        x (b,c,y,x) f32 -> xt (b, y*64+x, c) bf16 [NHWC]
//  blocks [4096, 4096+32):  w_deform -> fragment-linear bf16 wfrag
// ---------------------------------------------------------------------------
#define SWPAD 1156
__global__ void fa_prep(const float* __restrict__ x, const float* __restrict__ w,
                        __bf16* __restrict__ xt, __bf16* __restrict__ wfrag) {
    const int bid = blockIdx.x, t = threadIdx.x;
    __shared__ __bf16 sw[16 * SWPAD];
    if (bid < 4096) {
        const int c8q = bid & 7, hwt = (bid >> 3) & 63, b = bid >> 9;
        const int hw = hwt * 64 + (t & 63);
        const int c8 = c8q * 4 + (t >> 6);
        const float* xp = x + ((size_t)(b * CIN + c8 * 8) << 12) + hw;
        bf16x8 v;
#pragma unroll
        for (int j = 0; j < 8; j++) v[j] = (__bf16)xp[(size_t)j << 12];
        *(bf16x8*)&xt[(((size_t)b << 12) + hw) * 256 + c8 * 8] = v;
    } else {
        const int mt = (bid - 4096) >> 1, gh = (bid - 4096) & 1;
        const int o0 = mt * 16, g0 = gh * 2;
        const int r = t >> 4, tr = t & 15;
        const float* wp = w + (size_t)(o0 + r) * (CIN * Kn) + g0 * (CPG * Kn);
#pragma unroll
        for (int it = 0; it < 18; it++) {
            int off = it * 64 + tr * 4;
            float4 v = *(const float4*)(wp + off);
            __bf16* d = &sw[r * SWPAD + off];
            d[0] = (__bf16)v.x; d[1] = (__bf16)v.y;
            d[2] = (__bf16)v.z; d[3] = (__bf16)v.w;
        }
        __syncthreads();
#pragma unroll
        for (int it = 0; it < 9; it++) {
            int chunk = it * 256 + t;
            int lane = chunk & 63, ks = (chunk >> 6) & 1, gkl = chunk >> 7;
            int gl = gkl / Kn, k = gkl - gl * Kn;
            int gk = g0 * Kn + gkl;
            int ol = lane & 15;
            int cbase = ks * 32 + (lane >> 4) * 8;
            bf16x8 v;
#pragma unroll
            for (int j = 0; j < 8; j++)
                v[j] = sw[ol * SWPAD + (gl * CPG + cbase + j) * Kn + k];
            *(bf16x8*)&wfrag[(((size_t)gk * 16 + mt) * 2 + ks) * 512 + lane * 8] = v;
        }
    }
}

// ---------------------------------------------------------------------------
// Main: 256 blocks x 1024 threads. Block = bp*64 + h (bp = b-pair).
// N = 128 (2 b x 64 w); M = 256. 16 waves: wid_m (8) x wid_n (2).
// K-loop gk 0..35; meta phase-buffered per group (gk/9 == g).
// ---------------------------------------------------------------------------
__global__ __launch_bounds__(1024, 4)
void fa_main(const __bf16* __restrict__ xt, const float* __restrict__ shp,
             const float* __restrict__ w_off, const __bf16* __restrict__ wfrag,
             float* __restrict__ out) {
    const int blk = blockIdx.x;
    const int bp = blk >> 6, h = blk & 63;
    const int t = threadIdx.x;
    const int wid = t >> 6, lane = t & 63;
    const int wid_m = wid & 7, wid_n = wid >> 3;
    const int col = lane & 15, quad = lane >> 4;
    const int cg = t & 7, nl = t >> 3;              // staging: (cg, n) 8x128

    __shared__ __align__(16) int4 s_meta[9 * 128];        // 18432 B (1 phase)
    __shared__ __align__(16) __bf16 sB[2][128 * 64];      // 32768 B
    __shared__ float s_shp[2 * 4 * 64];                   //  2048 B
    __shared__ float s_woff[GK * 8];                      //  1152 B

    // ---- stage shp slice (2 b x 4 c x 64 w at row h) + all 288 w_off ----
    if (t < 512) {
        int bb = t >> 8, c = (t >> 6) & 3, wl = t & 63;
        s_shp[t] = shp[(((bp * 2 + bb) * 4 + c) << 12) + h * Wn + wl];
    }
    for (int u = t; u < GK * 8; u += 1024) s_woff[u] = w_off[u];
    __syncthreads();

    // ---- phase meta: records for gk in [9p, 9p+9), index (gk%9)*128+n ----
    auto computeMeta = [&](int p) {
        for (int i = t; i < 9 * 128; i += 1024) {
            int gkl = i >> 7, n = i & 127;
            int bb = n >> 6, wl = n & 63;
            int gk = p * 9 + gkl;
            int ky = gkl / 3, kx = gkl - ky * 3;
            float dy = 0.f, dx = 0.f;
#pragma unroll
            for (int c = 0; c < 4; c++) {
                float sv = s_shp[(bb * 4 + c) * 64 + wl];
                dy = fmaf(s_woff[gk * 8 + c],     sv, dy);
                dx = fmaf(s_woff[gk * 8 + 4 + c], sv, dx);
            }
            float py = (float)(h + ky - 1) + dy;
            float px = (float)(wl + kx - 1) + dx;
            float y0 = floorf(py), x0 = floorf(px);
            float fy = py - y0, fx = px - x0;
            int iy = (int)y0, ix = (int)x0;
            bool y0v = (unsigned)iy       < (unsigned)Hn;
            bool y1v = (unsigned)(iy + 1) < (unsigned)Hn;
            bool x0v = (unsigned)ix       < (unsigned)Wn;
            bool x1v = (unsigned)(ix + 1) < (unsigned)Wn;
            int yc0 = min(max(iy, 0), Hn - 1), yc1 = min(max(iy + 1, 0), Hn - 1);
            int xc0 = min(max(ix, 0), Wn - 1), xc1 = min(max(ix + 1, 0), Wn - 1);
            int l00 = yc0 * Wn + xc0, l01 = yc0 * Wn + xc1;
            int l10 = yc1 * Wn + xc0, l11 = yc1 * Wn + xc1;
            float wy1 = fy, wy0 = 1.f - fy, wx1 = fx, wx0 = 1.f - fx;
            float w00 = (y0v && x0v) ? wy0 * wx0 : 0.f;
            float w01 = (y0v && x1v) ? wy0 * wx1 : 0.f;
            float w10 = (y1v && x0v) ? wy1 * wx0 : 0.f;
            float w11 = (y1v && x1v) ? wy1 * wx1 : 0.f;
            f16x2 p0, p1;
            p0.x = (_Float16)w00; p0.y = (_Float16)w01;
            p1.x = (_Float16)w10; p1.y = (_Float16)w11;
            s_meta[i] = make_int4(l00 | (l01 << 16), l10 | (l11 << 16),
                                  __builtin_bit_cast(int, p0),
                                  __builtin_bit_cast(int, p1));
        }
    };

    bf16x8 c4[4];
    int2   amv;

    auto issue = [&](int gk) {
        int g = gk / 9;                      // phase == group
        int4 mv = s_meta[(gk - g * 9) * 128 + nl];
        amv.x = mv.z; amv.y = mv.w;
        int b = bp * 2 + (nl >> 6);
        const __bf16* base = xt + (((size_t)b << 12)) * 256 + g * CPG + cg * 8;
        c4[0] = *(const bf16x8*)(base + (size_t)(mv.x & 0xffff) * 256);
        c4[1] = *(const bf16x8*)(base + (size_t)((unsigned)mv.x >> 16) * 256);
        c4[2] = *(const bf16x8*)(base + (size_t)(mv.y & 0xffff) * 256);
        c4[3] = *(const bf16x8*)(base + (size_t)((unsigned)mv.y >> 16) * 256);
    };
    auto commit = [&](int buf) {
        f16x2 h0 = __builtin_bit_cast(f16x2, amv.x);
        f16x2 h1 = __builtin_bit_cast(f16x2, amv.y);
        float w00 = (float)h0.x, w01 = (float)h0.y;
        float w10 = (float)h1.x, w11 = (float)h1.y;
        bf16x8 r;
#pragma unroll
        for (int j = 0; j < 8; j++) {
            float v = w00 * (float)c4[0][j] + w01 * (float)c4[1][j]
                    + w10 * (float)c4[2][j] + w11 * (float)c4[3][j];
            r[j] = (__bf16)v;
        }
        *(bf16x8*)&sB[buf][(nl * 8 + (cg ^ (nl & 7))) * 8] = r;
    };

    f32x4 acc[2][4];
#pragma unroll
    for (int mt = 0; mt < 2; mt++)
#pragma unroll
        for (int nt = 0; nt < 4; nt++) acc[mt][nt] = (f32x4){0.f, 0.f, 0.f, 0.f};

    computeMeta(0);
    __syncthreads();            // meta phase 0 visible

    issue(0);
    commit(0);                  // sB[0] = tile 0
    issue(1);                   // corners(1) in regs
    __syncthreads();

    for (int gk = 0; gk < GK; gk++) {
        const int buf = gk & 1;
        // 1) A-frags for THIS gk
        const __bf16* wbase = wfrag + (((size_t)gk * 16 + wid_m * 2) * 2) * 512;
        bf16x8 af[2][2];
#pragma unroll
        for (int ks = 0; ks < 2; ks++)
#pragma unroll
            for (int mt = 0; mt < 2; mt++)
                af[ks][mt] = *(const bf16x8*)(wbase + ((size_t)(mt * 2 + ks) * 64 + lane) * 8);
        // 2) interp gk+1 (corners landed last iter) -> other buffer
        if (gk + 1 < GK) commit(buf ^ 1);
        // 2b) phase boundary: old phase's meta fully consumed (last read was
        //     issue(gk+1) at iter gk-1); compute next phase, then barrier.
        if (gk == 7 || gk == 16 || gk == 25) {
            computeMeta((gk + 2) / 9);
            __syncthreads();
        }
        // 3) corner loads for gk+2
        if (gk + 2 < GK) issue(gk + 2);
        // 4) MFMA on buf
#pragma unroll
        for (int ks = 0; ks < 2; ks++) {
            bf16x8 bfv[4];
#pragma unroll
            for (int nt = 0; nt < 4; nt++) {
                int n = wid_n * 64 + nt * 16 + col;
                int cq8 = ks * 4 + quad;
                bfv[nt] = *(const bf16x8*)&sB[buf][(n * 8 + (cq8 ^ (n & 7))) * 8];
            }
#pragma unroll
            for (int mt = 0; mt < 2; mt++)
#pragma unroll
                for (int nt = 0; nt < 4; nt++)
                    acc[mt][nt] = __builtin_amdgcn_mfma_f32_16x16x32_bf16(
                        af[ks][mt], bfv[nt], acc[mt][nt], 0, 0, 0);
        }
        __syncthreads();
    }

    // ---- epilogue: o = wid_m*32 + mt*16 + quad*4 + r ; b = bp*2 + wid_n ----
    const int b = bp * 2 + wid_n;
#pragma unroll
    for (int mt = 0; mt < 2; mt++)
#pragma unroll
        for (int r = 0; r < 4; r++) {
            int o = wid_m * 32 + mt * 16 + quad * 4 + r;
#pragma unroll
            for (int nt = 0; nt < 4; nt++) {
                int w = nt * 16 + col;
                out[(((size_t)(b * COUT + o)) << 12) + h * Wn + w] =
                    fmaxf(acc[mt][nt][r], 0.f);
            }
        }
}

// ---------------------------------------------------------------------------
extern "C" void kernel_launch(void* const* d_in, const int* in_sizes, int n_in,
                              void* d_out, int out_size, void* d_ws, size_t ws_size,
                              hipStream_t stream) {
    const float* x     = (const float*)d_in[0];
    const float* shp   = (const float*)d_in[1];
    const float* w_off = (const float*)d_in[2];
    const float* w_def = (const float*)d_in[3];
    float* out = (float*)d_out;
    __bf16* wfrag = (__bf16*)d_ws;                         // 1.18 MB
    __bf16* xt    = (__bf16*)((char*)d_ws + (2u << 20));   // 16.8 MB

    fa_prep<<<4096 + 32, 256, 0, stream>>>(x, w_def, xt, wfrag);
    fa_main<<<256, 1024, 0, stream>>>(xt, shp, w_off, wfrag, out);
}

// Round 10
// 147.740 us; speedup vs baseline: 1.0269x; 1.0269x over previous
//
#include <hip/hip_runtime.h>
#include <hip/hip_bf16.h>

// FeatureAlign deformable 3x3 conv, G=4, PAD=1.
// R10 = R8 scaffold (512 blk x 512 thr, 2 blocks/CU, full meta in LDS,
// 2-deep corner prefetch, 1 barrier/iter) with:
//  - f16 everywhere in the sample path: xt/wfrag/alphas f16, interp via
//    packed v_pk_fma_f16 (halves commit VALU; f16 10-bit mantissa > bf16).
//  - mfma_f32_32x32x16_f16: same FLOPs, half the MFMA instructions, higher
//    measured rate (2382 vs 2075 TF).
// R9's N=128 / 1-block/CU layout REVERTED (regressed: barrier drain with no
// co-resident block).

#define Bn   8
#define CIN  256
#define COUT 256
#define Hn   64
#define Wn   64
#define Gn   4
#define Kn   9
#define CPG  64
#define GK   36

typedef _Float16 f16x8 __attribute__((ext_vector_type(8)));
typedef _Float16 f16x2 __attribute__((ext_vector_type(2)));
typedef float    f32x16 __attribute__((ext_vector_type(16)));

static __device__ __forceinline__ f16x2 pair_of(const f16x8& v, int r) {
    int4 u = __builtin_bit_cast(int4, v);
    int  p = (r == 0) ? u.x : (r == 1) ? u.y : (r == 2) ? u.z : u.w;
    return __builtin_bit_cast(f16x2, p);
}

// ---------------------------------------------------------------------------
// Fused prep.
//  blocks [0, 4096):        x (b,c,y,x) f32 -> xt (b, y*64+x, c) f16 [NHWC]
//  blocks [4096, 4096+32):  w_deform -> fragment-linear f16 wfrag for
//    mfma_32x32x16: wfrag[((gk*8 + mt8)*4 + ks4)*512 + lane*8 + j]
//    o = mt8*32 + (lane&31), c = ks4*16 + (lane>>5)*8 + j.
//    Block = (mt8, g): 32 o-rows x 576 contiguous floats, LDS transpose.
// ---------------------------------------------------------------------------
#define SWPAD 578
__global__ void fa_prep(const float* __restrict__ x, const float* __restrict__ w,
                        _Float16* __restrict__ xt, _Float16* __restrict__ wfrag) {
    const int bid = blockIdx.x, t = threadIdx.x;
    __shared__ _Float16 sw[32 * SWPAD];
    if (bid < 4096) {
        const int c8q = bid & 7, hwt = (bid >> 3) & 63, b = bid >> 9;
        const int hw = hwt * 64 + (t & 63);
        const int c8 = c8q * 4 + (t >> 6);
        const float* xp = x + ((size_t)(b * CIN + c8 * 8) << 12) + hw;
        f16x8 v;
#pragma unroll
        for (int j = 0; j < 8; j++) v[j] = (_Float16)xp[(size_t)j << 12];
        *(f16x8*)&xt[(((size_t)b << 12) + hw) * 256 + c8 * 8] = v;
    } else {
        const int bid2 = bid - 4096;
        const int mt8 = bid2 >> 2, g = bid2 & 3;
        // read: 32 o-rows x 576 contiguous floats (one g-slice), coalesced
        const int r = t >> 3, tr = t & 7;
        const float* wp = w + (size_t)(mt8 * 32 + r) * (CIN * Kn) + g * (CPG * Kn);
#pragma unroll
        for (int it = 0; it < 18; it++) {
            int off = it * 32 + tr * 4;
            float4 v = *(const float4*)(wp + off);
            _Float16* d = &sw[r * SWPAD + off];
            d[0] = (_Float16)v.x; d[1] = (_Float16)v.y;
            d[2] = (_Float16)v.z; d[3] = (_Float16)v.w;
        }
        __syncthreads();
        // write: 2304 vec-chunks (9 k x 4 ks4 x 64 lanes), 9 per thread
#pragma unroll
        for (int it = 0; it < 9; it++) {
            int chunk = it * 256 + t;
            int lane = chunk & 63, ks4 = (chunk >> 6) & 3, k9 = chunk >> 8;
            int gk = g * Kn + k9;
            int ol = lane & 31;
            int cbase = ks4 * 16 + (lane >> 5) * 8;
            f16x8 v;
#pragma unroll
            for (int j = 0; j < 8; j++)
                v[j] = sw[ol * SWPAD + (cbase + j) * Kn + k9];
            *(f16x8*)&wfrag[(((size_t)gk * 8 + mt8) * 4 + ks4) * 512 + lane * 8] = v;
        }
    }
}

// ---------------------------------------------------------------------------
// Main: 512 blocks x 512 threads. Block = bp*128 + h*2 + wh.
// N = 64 (2 b x 32 w); M = 256 over 8 waves (32 o-rows each, 32x32 MFMA).
// ---------------------------------------------------------------------------
__global__ __launch_bounds__(512, 4)
void fa_main(const _Float16* __restrict__ xt, const float* __restrict__ shp,
             const float* __restrict__ w_off, const _Float16* __restrict__ wfrag,
             float* __restrict__ out) {
    const int blk = blockIdx.x;
    const int bp = blk >> 7, h = (blk >> 1) & 63, wh = blk & 1;
    const int w0 = wh * 32;
    const int t = threadIdx.x;
    const int wid = t >> 6, lane = t & 63;
    const int l31 = lane & 31, lhi = lane >> 5;
    const int cg = t & 7, nl = (t >> 3) & 63;

    __shared__ __align__(16) int4 s_meta[GK * 64];        // 36864 B
    __shared__ __align__(16) _Float16 sB[2][64 * 64];     // 16384 B
    __shared__ float s_shp[2 * 4 * 32];                   //  1024 B
    __shared__ float s_woff[GK * 8];                      //  1152 B

    // ---- stage shp slice (2 b x 4 c x 32 w at row h) + all 288 w_off ----
    if (t < 256) {
        int bb = t >> 7, c = (t >> 5) & 3, wl = t & 31;
        s_shp[t] = shp[(((bp * 2 + bb) * 4 + c) << 12) + h * Wn + w0 + wl];
    }
    for (int u = t; u < GK * 8; u += 512) s_woff[u] = w_off[u];
    __syncthreads();

    // ---- meta: one 16B record per (gk, n): {lin01, lin23, alpha f16x4} ----
    for (int i = t; i < GK * 64; i += 512) {
        int gk = i >> 6, n = i & 63;
        int bb = n >> 5, wl = n & 31;
        int g = gk / Kn, k = gk - g * Kn;
        int ky = k / 3, kx = k - ky * 3;
        float dy = 0.f, dx = 0.f;
#pragma unroll
        for (int c = 0; c < 4; c++) {
            float sv = s_shp[(bb * 4 + c) * 32 + wl];
            dy = fmaf(s_woff[gk * 8 + c],     sv, dy);
            dx = fmaf(s_woff[gk * 8 + 4 + c], sv, dx);
        }
        float py = (float)(h + ky - 1) + dy;
        float px = (float)(w0 + wl + kx - 1) + dx;
        float y0 = floorf(py), x0 = floorf(px);
        float fy = py - y0, fx = px - x0;
        int iy = (int)y0, ix = (int)x0;
        bool y0v = (unsigned)iy       < (unsigned)Hn;
        bool y1v = (unsigned)(iy + 1) < (unsigned)Hn;
        bool x0v = (unsigned)ix       < (unsigned)Wn;
        bool x1v = (unsigned)(ix + 1) < (unsigned)Wn;
        int yc0 = min(max(iy, 0), Hn - 1), yc1 = min(max(iy + 1, 0), Hn - 1);
        int xc0 = min(max(ix, 0), Wn - 1), xc1 = min(max(ix + 1, 0), Wn - 1);
        int l00 = yc0 * Wn + xc0, l01 = yc0 * Wn + xc1;
        int l10 = yc1 * Wn + xc0, l11 = yc1 * Wn + xc1;
        float wy1 = fy, wy0 = 1.f - fy, wx1 = fx, wx0 = 1.f - fx;
        float w00 = (y0v && x0v) ? wy0 * wx0 : 0.f;
        float w01 = (y0v && x1v) ? wy0 * wx1 : 0.f;
        float w10 = (y1v && x0v) ? wy1 * wx0 : 0.f;
        float w11 = (y1v && x1v) ? wy1 * wx1 : 0.f;
        f16x2 p0, p1;
        p0.x = (_Float16)w00; p0.y = (_Float16)w01;
        p1.x = (_Float16)w10; p1.y = (_Float16)w11;
        s_meta[i] = make_int4(l00 | (l01 << 16), l10 | (l11 << 16),
                              __builtin_bit_cast(int, p0),
                              __builtin_bit_cast(int, p1));
    }

    f16x8 c4[4];
    int2  amv;

    auto issue = [&](int gk) {
        int4 mv = s_meta[gk * 64 + nl];
        amv.x = mv.z; amv.y = mv.w;
        int b = bp * 2 + (nl >> 5);
        int g = gk / Kn;
        const _Float16* base = xt + (((size_t)b << 12)) * 256 + g * CPG + cg * 8;
        c4[0] = *(const f16x8*)(base + (size_t)(mv.x & 0xffff) * 256);
        c4[1] = *(const f16x8*)(base + (size_t)((unsigned)mv.x >> 16) * 256);
        c4[2] = *(const f16x8*)(base + (size_t)(mv.y & 0xffff) * 256);
        c4[3] = *(const f16x8*)(base + (size_t)((unsigned)mv.y >> 16) * 256);
    };
    auto commit = [&](int buf) {
        f16x2 h0 = __builtin_bit_cast(f16x2, amv.x);
        f16x2 h1 = __builtin_bit_cast(f16x2, amv.y);
        f16x2 a00; a00.x = h0.x; a00.y = h0.x;
        f16x2 a01; a01.x = h0.y; a01.y = h0.y;
        f16x2 a10; a10.x = h1.x; a10.y = h1.x;
        f16x2 a11; a11.x = h1.y; a11.y = h1.y;
        int4 rp;
#pragma unroll
        for (int r = 0; r < 4; r++) {
            f16x2 s = a00 * pair_of(c4[0], r);
            s = a01 * pair_of(c4[1], r) + s;
            s = a10 * pair_of(c4[2], r) + s;
            s = a11 * pair_of(c4[3], r) + s;
            int sv = __builtin_bit_cast(int, s);
            if (r == 0) rp.x = sv; else if (r == 1) rp.y = sv;
            else if (r == 2) rp.z = sv; else rp.w = sv;
        }
        *(int4*)&sB[buf][(nl * 8 + (cg ^ (nl & 7))) * 8] = rp;
    };

    f32x16 acc[2];
#pragma unroll
    for (int nt = 0; nt < 2; nt++)
#pragma unroll
        for (int r = 0; r < 16; r++) acc[nt][r] = 0.f;

    __syncthreads();            // meta visible

    issue(0);
    commit(0);                  // sB[0] = tile 0
    issue(1);                   // corners(1) in regs
    __syncthreads();

    for (int gk = 0; gk < GK; gk++) {
        const int buf = gk & 1;
        // 1) A-frags for THIS gk (oldest vm loads; corner loads stay in
        //    flight across the MFMA's wait)
        const _Float16* wbase = wfrag + (((size_t)gk * 8 + wid) * 4) * 512;
        f16x8 af[4];
#pragma unroll
        for (int ks = 0; ks < 4; ks++)
            af[ks] = *(const f16x8*)(wbase + ((size_t)ks * 64 + lane) * 8);
        // 2) interp gk+1 (corners landed last iter) -> other buffer
        if (gk + 1 < GK) commit(buf ^ 1);
        // 3) corner loads for gk+2
        if (gk + 2 < GK) issue(gk + 2);
        // 4) MFMA on buf: 4 K-steps x 2 n-tiles of 32x32x16
#pragma unroll
        for (int ks = 0; ks < 4; ks++) {
            int cb = ks * 2 + lhi;
#pragma unroll
            for (int nt = 0; nt < 2; nt++) {
                int n = nt * 32 + l31;
                f16x8 bf = *(const f16x8*)&sB[buf][(n * 8 + (cb ^ (n & 7))) * 8];
                acc[nt] = __builtin_amdgcn_mfma_f32_32x32x16_f16(
                    af[ks], bf, acc[nt], 0, 0, 0);
            }
        }
        __syncthreads();
    }

    // ---- epilogue: C/D 32x32: col=lane&31, row=(reg&3)+8*(reg>>2)+4*lhi ----
#pragma unroll
    for (int nt = 0; nt < 2; nt++) {
        int b = bp * 2 + nt;
        float* op = out + ((size_t)b * COUT << 12) + h * Wn + w0 + l31;
#pragma unroll
        for (int reg = 0; reg < 16; reg++) {
            int row = (reg & 3) + 8 * (reg >> 2) + 4 * lhi;
            int o = wid * 32 + row;
            op[(size_t)o << 12] = fmaxf(acc[nt][reg], 0.f);
        }
    }
}

// ---------------------------------------------------------------------------
extern "C" void kernel_launch(void* const* d_in, const int* in_sizes, int n_in,
                              void* d_out, int out_size, void* d_ws, size_t ws_size,
                              hipStream_t stream) {
    const float* x     = (const float*)d_in[0];
    const float* shp   = (const float*)d_in[1];
    const float* w_off = (const float*)d_in[2];
    const float* w_def = (const float*)d_in[3];
    float* out = (float*)d_out;
    _Float16* wfrag = (_Float16*)d_ws;                         // 1.18 MB
    _Float16* xt    = (_Float16*)((char*)d_ws + (2u << 20));   // 16.8 MB

    fa_prep<<<4096 + 32, 256, 0, stream>>>(x, w_def, xt, wfrag);
    fa_main<<<512, 512, 0, stream>>>(xt, shp, w_off, wfrag, out);
}

// Round 11
// 147.618 us; speedup vs baseline: 1.0277x; 1.0008x over previous
//
#include <hip/hip_runtime.h>
#include <hip/hip_bf16.h>

// FeatureAlign deformable 3x3 conv, G=4, PAD=1.
// R11 = R10 with the K-loop __syncthreads() replaced by a NON-DRAINING
// barrier (s_waitcnt lgkmcnt(0); s_barrier). HIP's __syncthreads emits
// s_waitcnt vmcnt(0) before s_barrier, forcing every iteration to gate on
// the slowest outstanding corner gather -- that drain is the ~4080 cyc/iter
// floor R8/R10 both hit (VALU dropped 41->24% in R10 with zero time change).
// Cross-wave visibility only needs LDS (sB commits) => lgkmcnt(0) suffices;
// corner/A-frag loads land in private registers guarded by the compiler's
// register-dependency waitcnts. Gathers now stay in flight across barriers.

#define Bn   8
#define CIN  256
#define COUT 256
#define Hn   64
#define Wn   64
#define Gn   4
#define Kn   9
#define CPG  64
#define GK   36

typedef _Float16 f16x8 __attribute__((ext_vector_type(8)));
typedef _Float16 f16x2 __attribute__((ext_vector_type(2)));
typedef float    f32x16 __attribute__((ext_vector_type(16)));

// LDS-only barrier: wait for DS ops, do NOT drain vmcnt.
#define BAR_LDS() asm volatile("s_waitcnt lgkmcnt(0)\n\ts_barrier" ::: "memory")

static __device__ __forceinline__ f16x2 pair_of(const f16x8& v, int r) {
    int4 u = __builtin_bit_cast(int4, v);
    int  p = (r == 0) ? u.x : (r == 1) ? u.y : (r == 2) ? u.z : u.w;
    return __builtin_bit_cast(f16x2, p);
}

// ---------------------------------------------------------------------------
// Fused prep (unchanged from R10).
//  blocks [0, 4096):        x (b,c,y,x) f32 -> xt (b, y*64+x, c) f16 [NHWC]
//  blocks [4096, 4096+32):  w_deform -> fragment-linear f16 wfrag for
//    mfma_32x32x16: wfrag[((gk*8 + mt8)*4 + ks4)*512 + lane*8 + j]
//    o = mt8*32 + (lane&31), c = ks4*16 + (lane>>5)*8 + j.
// ---------------------------------------------------------------------------
#define SWPAD 578
__global__ void fa_prep(const float* __restrict__ x, const float* __restrict__ w,
                        _Float16* __restrict__ xt, _Float16* __restrict__ wfrag) {
    const int bid = blockIdx.x, t = threadIdx.x;
    __shared__ _Float16 sw[32 * SWPAD];
    if (bid < 4096) {
        const int c8q = bid & 7, hwt = (bid >> 3) & 63, b = bid >> 9;
        const int hw = hwt * 64 + (t & 63);
        const int c8 = c8q * 4 + (t >> 6);
        const float* xp = x + ((size_t)(b * CIN + c8 * 8) << 12) + hw;
        f16x8 v;
#pragma unroll
        for (int j = 0; j < 8; j++) v[j] = (_Float16)xp[(size_t)j << 12];
        *(f16x8*)&xt[(((size_t)b << 12) + hw) * 256 + c8 * 8] = v;
    } else {
        const int bid2 = bid - 4096;
        const int mt8 = bid2 >> 2, g = bid2 & 3;
        const int r = t >> 3, tr = t & 7;
        const float* wp = w + (size_t)(mt8 * 32 + r) * (CIN * Kn) + g * (CPG * Kn);
#pragma unroll
        for (int it = 0; it < 18; it++) {
            int off = it * 32 + tr * 4;
            float4 v = *(const float4*)(wp + off);
            _Float16* d = &sw[r * SWPAD + off];
            d[0] = (_Float16)v.x; d[1] = (_Float16)v.y;
            d[2] = (_Float16)v.z; d[3] = (_Float16)v.w;
        }
        __syncthreads();
#pragma unroll
        for (int it = 0; it < 9; it++) {
            int chunk = it * 256 + t;
            int lane = chunk & 63, ks4 = (chunk >> 6) & 3, k9 = chunk >> 8;
            int gk = g * Kn + k9;
            int ol = lane & 31;
            int cbase = ks4 * 16 + (lane >> 5) * 8;
            f16x8 v;
#pragma unroll
            for (int j = 0; j < 8; j++)
                v[j] = sw[ol * SWPAD + (cbase + j) * Kn + k9];
            *(f16x8*)&wfrag[(((size_t)gk * 8 + mt8) * 4 + ks4) * 512 + lane * 8] = v;
        }
    }
}

// ---------------------------------------------------------------------------
// Main: 512 blocks x 512 threads. Block = bp*128 + h*2 + wh.
// N = 64 (2 b x 32 w); M = 256 over 8 waves (32 o-rows each, 32x32 MFMA).
// ---------------------------------------------------------------------------
__global__ __launch_bounds__(512, 4)
void fa_main(const _Float16* __restrict__ xt, const float* __restrict__ shp,
             const float* __restrict__ w_off, const _Float16* __restrict__ wfrag,
             float* __restrict__ out) {
    const int blk = blockIdx.x;
    const int bp = blk >> 7, h = (blk >> 1) & 63, wh = blk & 1;
    const int w0 = wh * 32;
    const int t = threadIdx.x;
    const int wid = t >> 6, lane = t & 63;
    const int l31 = lane & 31, lhi = lane >> 5;
    const int cg = t & 7, nl = (t >> 3) & 63;

    __shared__ __align__(16) int4 s_meta[GK * 64];        // 36864 B
    __shared__ __align__(16) _Float16 sB[2][64 * 64];     // 16384 B
    __shared__ float s_shp[2 * 4 * 32];                   //  1024 B
    __shared__ float s_woff[GK * 8];                      //  1152 B

    // ---- stage shp slice + all 288 w_off ----
    if (t < 256) {
        int bb = t >> 7, c = (t >> 5) & 3, wl = t & 31;
        s_shp[t] = shp[(((bp * 2 + bb) * 4 + c) << 12) + h * Wn + w0 + wl];
    }
    for (int u = t; u < GK * 8; u += 512) s_woff[u] = w_off[u];
    __syncthreads();

    // ---- meta: one 16B record per (gk, n): {lin01, lin23, alpha f16x4} ----
    for (int i = t; i < GK * 64; i += 512) {
        int gk = i >> 6, n = i & 63;
        int bb = n >> 5, wl = n & 31;
        int g = gk / Kn, k = gk - g * Kn;
        int ky = k / 3, kx = k - ky * 3;
        float dy = 0.f, dx = 0.f;
#pragma unroll
        for (int c = 0; c < 4; c++) {
            float sv = s_shp[(bb * 4 + c) * 32 + wl];
            dy = fmaf(s_woff[gk * 8 + c],     sv, dy);
            dx = fmaf(s_woff[gk * 8 + 4 + c], sv, dx);
        }
        float py = (float)(h + ky - 1) + dy;
        float px = (float)(w0 + wl + kx - 1) + dx;
        float y0 = floorf(py), x0 = floorf(px);
        float fy = py - y0, fx = px - x0;
        int iy = (int)y0, ix = (int)x0;
        bool y0v = (unsigned)iy       < (unsigned)Hn;
        bool y1v = (unsigned)(iy + 1) < (unsigned)Hn;
        bool x0v = (unsigned)ix       < (unsigned)Wn;
        bool x1v = (unsigned)(ix + 1) < (unsigned)Wn;
        int yc0 = min(max(iy, 0), Hn - 1), yc1 = min(max(iy + 1, 0), Hn - 1);
        int xc0 = min(max(ix, 0), Wn - 1), xc1 = min(max(ix + 1, 0), Wn - 1);
        int l00 = yc0 * Wn + xc0, l01 = yc0 * Wn + xc1;
        int l10 = yc1 * Wn + xc0, l11 = yc1 * Wn + xc1;
        float wy1 = fy, wy0 = 1.f - fy, wx1 = fx, wx0 = 1.f - fx;
        float w00 = (y0v && x0v) ? wy0 * wx0 : 0.f;
        float w01 = (y0v && x1v) ? wy0 * wx1 : 0.f;
        float w10 = (y1v && x0v) ? wy1 * wx0 : 0.f;
        float w11 = (y1v && x1v) ? wy1 * wx1 : 0.f;
        f16x2 p0, p1;
        p0.x = (_Float16)w00; p0.y = (_Float16)w01;
        p1.x = (_Float16)w10; p1.y = (_Float16)w11;
        s_meta[i] = make_int4(l00 | (l01 << 16), l10 | (l11 << 16),
                              __builtin_bit_cast(int, p0),
                              __builtin_bit_cast(int, p1));
    }

    f16x8 c4[4];
    int2  amv;

    auto issue = [&](int gk) {
        int4 mv = s_meta[gk * 64 + nl];
        amv.x = mv.z; amv.y = mv.w;
        int b = bp * 2 + (nl >> 5);
        int g = gk / Kn;
        const _Float16* base = xt + (((size_t)b << 12)) * 256 + g * CPG + cg * 8;
        c4[0] = *(const f16x8*)(base + (size_t)(mv.x & 0xffff) * 256);
        c4[1] = *(const f16x8*)(base + (size_t)((unsigned)mv.x >> 16) * 256);
        c4[2] = *(const f16x8*)(base + (size_t)(mv.y & 0xffff) * 256);
        c4[3] = *(const f16x8*)(base + (size_t)((unsigned)mv.y >> 16) * 256);
    };
    auto commit = [&](int buf) {
        f16x2 h0 = __builtin_bit_cast(f16x2, amv.x);
        f16x2 h1 = __builtin_bit_cast(f16x2, amv.y);
        f16x2 a00; a00.x = h0.x; a00.y = h0.x;
        f16x2 a01; a01.x = h0.y; a01.y = h0.y;
        f16x2 a10; a10.x = h1.x; a10.y = h1.x;
        f16x2 a11; a11.x = h1.y; a11.y = h1.y;
        int4 rp;
#pragma unroll
        for (int r = 0; r < 4; r++) {
            f16x2 s = a00 * pair_of(c4[0], r);
            s = a01 * pair_of(c4[1], r) + s;
            s = a10 * pair_of(c4[2], r) + s;
            s = a11 * pair_of(c4[3], r) + s;
            int sv = __builtin_bit_cast(int, s);
            if (r == 0) rp.x = sv; else if (r == 1) rp.y = sv;
            else if (r == 2) rp.z = sv; else rp.w = sv;
        }
        *(int4*)&sB[buf][(nl * 8 + (cg ^ (nl & 7))) * 8] = rp;
    };

    f32x16 acc[2];
#pragma unroll
    for (int nt = 0; nt < 2; nt++)
#pragma unroll
        for (int r = 0; r < 16; r++) acc[nt][r] = 0.f;

    __syncthreads();            // meta visible

    issue(0);
    commit(0);                  // sB[0] = tile 0
    issue(1);                   // corners(1) in regs
    BAR_LDS();

    for (int gk = 0; gk < GK; gk++) {
        const int buf = gk & 1;
        // 1) A-frags for THIS gk
        const _Float16* wbase = wfrag + (((size_t)gk * 8 + wid) * 4) * 512;
        f16x8 af[4];
#pragma unroll
        for (int ks = 0; ks < 4; ks++)
            af[ks] = *(const f16x8*)(wbase + ((size_t)ks * 64 + lane) * 8);
        // 2) interp gk+1 (corners landed last iter) -> other buffer
        if (gk + 1 < GK) commit(buf ^ 1);
        // 3) corner loads for gk+2 (stay in flight across the barrier now)
        if (gk + 2 < GK) issue(gk + 2);
        // 4) MFMA on buf: 4 K-steps x 2 n-tiles of 32x32x16
#pragma unroll
        for (int ks = 0; ks < 4; ks++) {
            int cb = ks * 2 + lhi;
#pragma unroll
            for (int nt = 0; nt < 2; nt++) {
                int n = nt * 32 + l31;
                f16x8 bf = *(const f16x8*)&sB[buf][(n * 8 + (cb ^ (n & 7))) * 8];
                acc[nt] = __builtin_amdgcn_mfma_f32_32x32x16_f16(
                    af[ks], bf, acc[nt], 0, 0, 0);
            }
        }
        BAR_LDS();              // LDS-only barrier: no vmcnt drain
    }

    // ---- epilogue: C/D 32x32: col=lane&31, row=(reg&3)+8*(reg>>2)+4*lhi ----
#pragma unroll
    for (int nt = 0; nt < 2; nt++) {
        int b = bp * 2 + nt;
        float* op = out + ((size_t)b * COUT << 12) + h * Wn + w0 + l31;
#pragma unroll
        for (int reg = 0; reg < 16; reg++) {
            int row = (reg & 3) + 8 * (reg >> 2) + 4 * lhi;
            int o = wid * 32 + row;
            op[(size_t)o << 12] = fmaxf(acc[nt][reg], 0.f);
        }
    }
}

// ---------------------------------------------------------------------------
extern "C" void kernel_launch(void* const* d_in, const int* in_sizes, int n_in,
                              void* d_out, int out_size, void* d_ws, size_t ws_size,
                              hipStream_t stream) {
    const float* x     = (const float*)d_in[0];
    const float* shp   = (const float*)d_in[1];
    const float* w_off = (const float*)d_in[2];
    const float* w_def = (const float*)d_in[3];
    float* out = (float*)d_out;
    _Float16* wfrag = (_Float16*)d_ws;                         // 1.18 MB
    _Float16* xt    = (_Float16*)((char*)d_ws + (2u << 20));   // 16.8 MB

    fa_prep<<<4096 + 32, 256, 0, stream>>>(x, w_def, xt, wfrag);
    fa_main<<<512, 512, 0, stream>>>(xt, shp, w_off, wfrag, out);
}